// Round 1
// baseline (240.256 us; speedup 1.0000x reference)
//
#include <hip/hip_runtime.h>
#include <hip/hip_bf16.h>

typedef __attribute__((ext_vector_type(8))) short short8;
typedef __attribute__((ext_vector_type(4))) float f32x4;

#define D_   1024
#define SEQ_ 2048
#define NB_  2
#define NH_  16
#define HD_  64

using u16 = unsigned short;

static __device__ __forceinline__ u16 f2bf(float f) {
    union { __bf16 h; u16 u; } cv;
    cv.h = (__bf16)f;
    return cv.u;
}
static __device__ __forceinline__ float bf2f(u16 u) {
    union { unsigned int i; float f; } v;
    v.i = ((unsigned int)u) << 16;
    return v.f;
}

// ---------------- f32 -> bf16 bulk convert (memory-bound) ----------------
__global__ __launch_bounds__(256)
void cvt_kernel(const float* __restrict__ in, u16* __restrict__ out) {
    int i = (blockIdx.x * 256 + threadIdx.x) * 8;
    float4 a = *(const float4*)&in[i];
    float4 b = *(const float4*)&in[i + 4];
    short8 o;
    o[0] = (short)f2bf(a.x); o[1] = (short)f2bf(a.y);
    o[2] = (short)f2bf(a.z); o[3] = (short)f2bf(a.w);
    o[4] = (short)f2bf(b.x); o[5] = (short)f2bf(b.y);
    o[6] = (short)f2bf(b.z); o[7] = (short)f2bf(b.w);
    *(short8*)&out[i] = o;
}

// ---------------- bf16 GEMM: Y[m][n] = sum_k A[m][k] * W[n][k] ----------------
// 128x128 tile, BK=32, 4 waves (2x2), each wave 64x64 = 4x4 fragments of 16x16x32.
// Reg-staged double-buffered LDS, +8 bf16 pad (80B row stride -> 2-way bank alias, free).
template<int OUT_F32>
__global__ __launch_bounds__(256)
void gemm_bt(const u16* __restrict__ A,
             const u16* __restrict__ W0, const u16* __restrict__ W1, const u16* __restrict__ W2,
             void* __restrict__ Y0, void* __restrict__ Y1, void* __restrict__ Y2)
{
    const u16* W  = (blockIdx.z == 0) ? W0 : ((blockIdx.z == 1) ? W1 : W2);
    void*      Yv = (blockIdx.z == 0) ? Y0 : ((blockIdx.z == 1) ? Y1 : Y2);
    const int mBase = blockIdx.x * 128;
    const int nBase = blockIdx.y * 128;

    __shared__ u16 lA[2][128][40];
    __shared__ u16 lB[2][128][40];

    const int t    = threadIdx.x;
    const int lane = t & 63, wid = t >> 6;
    const int wr = wid >> 1, wc = wid & 1;
    const int lr = lane & 15, lg = lane >> 4;
    const int sr = t >> 2;          // staging row (chunk j adds 64)
    const int sc = (t & 3) * 8;     // staging col (8 bf16 per chunk)

    f32x4 acc[4][4];
#pragma unroll
    for (int m = 0; m < 4; ++m)
#pragma unroll
        for (int n = 0; n < 4; ++n) acc[m][n] = (f32x4){0.f, 0.f, 0.f, 0.f};

    short8 ra[2], rb[2];
    // prologue: stage kt=0
#pragma unroll
    for (int j = 0; j < 2; ++j) {
        ra[j] = *(const short8*)&A[(size_t)(mBase + sr + 64 * j) * D_ + sc];
        rb[j] = *(const short8*)&W[(size_t)(nBase + sr + 64 * j) * D_ + sc];
    }
#pragma unroll
    for (int j = 0; j < 2; ++j) {
        *(short8*)&lA[0][sr + 64 * j][sc] = ra[j];
        *(short8*)&lB[0][sr + 64 * j][sc] = rb[j];
    }
    __syncthreads();

    int cur = 0;
    for (int kt = 0; kt < 32; ++kt) {
        if (kt < 31) {
#pragma unroll
            for (int j = 0; j < 2; ++j) {
                ra[j] = *(const short8*)&A[(size_t)(mBase + sr + 64 * j) * D_ + (kt + 1) * 32 + sc];
                rb[j] = *(const short8*)&W[(size_t)(nBase + sr + 64 * j) * D_ + (kt + 1) * 32 + sc];
            }
        }
        short8 af[4], bfv[4];
#pragma unroll
        for (int m = 0; m < 4; ++m)
            af[m] = *(const short8*)&lA[cur][wr * 64 + m * 16 + lr][lg * 8];
#pragma unroll
        for (int n = 0; n < 4; ++n)
            bfv[n] = *(const short8*)&lB[cur][wc * 64 + n * 16 + lr][lg * 8];
#pragma unroll
        for (int m = 0; m < 4; ++m)
#pragma unroll
            for (int n = 0; n < 4; ++n)
                acc[m][n] = __builtin_amdgcn_mfma_f32_16x16x32_bf16(af[m], bfv[n], acc[m][n], 0, 0, 0);
        if (kt < 31) {
#pragma unroll
            for (int j = 0; j < 2; ++j) {
                *(short8*)&lA[cur ^ 1][sr + 64 * j][sc] = ra[j];
                *(short8*)&lB[cur ^ 1][sr + 64 * j][sc] = rb[j];
            }
        }
        __syncthreads();
        cur ^= 1;
    }

    // epilogue: C layout col=lane&15, row=(lane>>4)*4+reg (m89-verified)
#pragma unroll
    for (int m = 0; m < 4; ++m)
#pragma unroll
        for (int n = 0; n < 4; ++n)
#pragma unroll
            for (int r = 0; r < 4; ++r) {
                int row = mBase + wr * 64 + m * 16 + lg * 4 + r;
                int col = nBase + wc * 64 + n * 16 + lr;
                if (OUT_F32)
                    ((float*)Yv)[(size_t)row * D_ + col] = acc[m][n][r];
                else
                    ((u16*)Yv)[(size_t)row * D_ + col] = f2bf(acc[m][n][r]);
            }
}

// ---------------- causal flash attention ----------------
// 64 q-rows per block, 4 waves x 16 rows, KVBLK=64, Hd=64.
__global__ __launch_bounds__(256)
void attn_fwd(const u16* __restrict__ Q, const u16* __restrict__ K,
              const u16* __restrict__ V, u16* __restrict__ O)
{
    const int qt = 31 - (int)blockIdx.x;   // heavy tiles dispatched first
    const int bh = blockIdx.y;
    const int b = bh >> 4, h = bh & 15;
    const int qbase = qt * 64;

    const size_t base = (size_t)b * SEQ_ * D_ + (size_t)h * HD_;
    const u16* Qb = Q + base;
    const u16* Kb = K + base;
    const u16* Vb = V + base;
    u16*       Ob = O + base;

    __shared__ u16 lK[64][72];      // [key][hd], pad 72 -> 2-way bank alias (free)
    __shared__ u16 lVt[64][72];     // transposed: [hd][key]
    __shared__ u16 lP[4][16][72];   // per-wave P tile

    const int t    = threadIdx.x;
    const int lane = t & 63, wid = t >> 6;
    const int lr = lane & 15, lg = lane >> 4;
    const int str = t >> 3;          // staging row 0..31 (+32 for j=1)
    const int stc = (t & 7) * 8;     // staging col

    // Q fragments, pre-scaled by 1/sqrt(64)=0.125 (exact in bf16: exponent shift)
    short8 qf[2];
    {
        const int qrow = qbase + wid * 16 + lr;
#pragma unroll
        for (int ks = 0; ks < 2; ++ks) {
            short8 v = *(const short8*)&Qb[(size_t)qrow * D_ + ks * 32 + lg * 8];
#pragma unroll
            for (int i = 0; i < 8; ++i)
                v[i] = (short)f2bf(bf2f((u16)v[i]) * 0.125f);
            qf[ks] = v;
        }
    }

    f32x4 accO[4];
#pragma unroll
    for (int n = 0; n < 4; ++n) accO[n] = (f32x4){0.f, 0.f, 0.f, 0.f};
    float m_r[4], l_r[4];
#pragma unroll
    for (int r = 0; r < 4; ++r) { m_r[r] = -__builtin_inff(); l_r[r] = 0.f; }

    for (int kt = 0; kt <= qt; ++kt) {
        const int kbase = kt * 64;
        // stage K tile (row-major) and V tile (transposed)
#pragma unroll
        for (int j = 0; j < 2; ++j) {
            int r = str + 32 * j;
            short8 kk = *(const short8*)&Kb[(size_t)(kbase + r) * D_ + stc];
            *(short8*)&lK[r][stc] = kk;
            short8 vv = *(const short8*)&Vb[(size_t)(kbase + r) * D_ + stc];
#pragma unroll
            for (int i = 0; i < 8; ++i) lVt[stc + i][r] = (u16)vv[i];
        }
        __syncthreads();

        // QK^T: A=Q rows, B[k=hd][col=key] = K[key][hd]
        f32x4 s[4];
#pragma unroll
        for (int n = 0; n < 4; ++n) {
            s[n] = (f32x4){0.f, 0.f, 0.f, 0.f};
#pragma unroll
            for (int ks = 0; ks < 2; ++ks) {
                short8 kf = *(const short8*)&lK[n * 16 + lr][ks * 32 + lg * 8];
                s[n] = __builtin_amdgcn_mfma_f32_16x16x32_bf16(qf[ks], kf, s[n], 0, 0, 0);
            }
        }
        // causal mask (only the diagonal tile has masked entries)
        if (kt == qt) {
#pragma unroll
            for (int n = 0; n < 4; ++n)
#pragma unroll
                for (int r = 0; r < 4; ++r) {
                    int key = kbase + n * 16 + lr;
                    int qr  = qbase + wid * 16 + lg * 4 + r;
                    if (key > qr) s[n][r] = -__builtin_inff();
                }
        }
        // online softmax: per-row stats; row r held by 16 lanes (same lane>>4)
        float tmax[4], alpha[4], rs[4];
#pragma unroll
        for (int r = 0; r < 4; ++r) {
            tmax[r] = fmaxf(fmaxf(s[0][r], s[1][r]), fmaxf(s[2][r], s[3][r]));
#pragma unroll
            for (int d = 1; d < 16; d <<= 1)
                tmax[r] = fmaxf(tmax[r], __shfl_xor(tmax[r], d));
            float mn = fmaxf(m_r[r], tmax[r]);
            alpha[r] = __expf(m_r[r] - mn);
            m_r[r]   = mn;
            rs[r]    = 0.f;
        }
#pragma unroll
        for (int n = 0; n < 4; ++n)
#pragma unroll
            for (int r = 0; r < 4; ++r) {
                float p = __expf(s[n][r] - m_r[r]);
                s[n][r] = p;
                rs[r] += p;
            }
#pragma unroll
        for (int r = 0; r < 4; ++r) {
#pragma unroll
            for (int d = 1; d < 16; d <<= 1) rs[r] += __shfl_xor(rs[r], d);
            l_r[r] = l_r[r] * alpha[r] + rs[r];
        }
        // P -> LDS (bf16), rescale O
#pragma unroll
        for (int n = 0; n < 4; ++n)
#pragma unroll
            for (int r = 0; r < 4; ++r) {
                lP[wid][lg * 4 + r][n * 16 + lr] = f2bf(s[n][r]);
                accO[n][r] *= alpha[r];
            }
        __syncthreads();

        // PV: A=P (row=q, k=key), B[k=key][col=hd] from lVt
#pragma unroll
        for (int ks = 0; ks < 2; ++ks) {
            short8 pa = *(const short8*)&lP[wid][lr][ks * 32 + lg * 8];
#pragma unroll
            for (int n = 0; n < 4; ++n) {
                short8 vf = *(const short8*)&lVt[n * 16 + lr][ks * 32 + lg * 8];
                accO[n] = __builtin_amdgcn_mfma_f32_16x16x32_bf16(pa, vf, accO[n], 0, 0, 0);
            }
        }
        __syncthreads();
    }

    // epilogue: O = acc / l
#pragma unroll
    for (int n = 0; n < 4; ++n)
#pragma unroll
        for (int r = 0; r < 4; ++r) {
            int qr = qbase + wid * 16 + lg * 4 + r;
            Ob[(size_t)qr * D_ + n * 16 + lr] = f2bf(accO[n][r] / l_r[r]);
        }
}

extern "C" void kernel_launch(void* const* d_in, const int* in_sizes, int n_in,
                              void* d_out, int out_size, void* d_ws, size_t ws_size,
                              hipStream_t stream)
{
    const float* x  = (const float*)d_in[0];
    const float* Wq = (const float*)d_in[1];
    const float* Wk = (const float*)d_in[2];
    const float* Wv = (const float*)d_in[3];
    const float* Wo = (const float*)d_in[4];
    float* out = (float*)d_out;

    const size_t NX = (size_t)NB_ * SEQ_ * D_;  // 4194304
    const size_t NW = (size_t)D_ * D_;          // 1048576

    // ws layout (bf16 elements), ~48 MiB total
    u16* xb  = (u16*)d_ws;
    u16* wqb = xb  + NX;
    u16* wkb = wqb + NW;
    u16* wvb = wkb + NW;
    u16* wob = wvb + NW;
    u16* Qb  = wob + NW;
    u16* Kb  = Qb  + NX;
    u16* Vb  = Kb  + NX;
    u16* Ab  = Vb  + NX;

    cvt_kernel<<<dim3(NX / 2048), dim3(256), 0, stream>>>(x,  xb);
    cvt_kernel<<<dim3(NW / 2048), dim3(256), 0, stream>>>(Wq, wqb);
    cvt_kernel<<<dim3(NW / 2048), dim3(256), 0, stream>>>(Wk, wkb);
    cvt_kernel<<<dim3(NW / 2048), dim3(256), 0, stream>>>(Wv, wvb);
    cvt_kernel<<<dim3(NW / 2048), dim3(256), 0, stream>>>(Wo, wob);

    // fused QKV projection: grid.z selects weight/output
    gemm_bt<0><<<dim3(32, 8, 3), dim3(256), 0, stream>>>(xb, wqb, wkb, wvb, Qb, Kb, Vb);

    // causal flash attention: x = q-tile (reversed), y = b*16+h
    attn_fwd<<<dim3(32, 32), dim3(256), 0, stream>>>(Qb, Kb, Vb, Ab);

    // output projection -> f32
    gemm_bt<1><<<dim3(32, 8, 1), dim3(256), 0, stream>>>(Ab, wob, wob, wob, out, out, out);
}

// Round 2
// 148.438 us; speedup vs baseline: 1.6186x; 1.6186x over previous
//
#include <hip/hip_runtime.h>
#include <hip/hip_bf16.h>

typedef __attribute__((ext_vector_type(8))) short short8;
typedef __attribute__((ext_vector_type(4))) float f32x4;

#define D_   1024
#define SEQ_ 2048
#define NB_  2
#define NH_  16
#define HD_  64
#define LDV_ 4096   // V^T row stride (= B*S)

using u16 = unsigned short;

static __device__ __forceinline__ u16 f2bf(float f) {
    union { __bf16 h; u16 u; } cv;
    cv.h = (__bf16)f;
    return cv.u;
}
static __device__ __forceinline__ float bf2f(u16 u) {
    union { unsigned int i; float f; } v;
    v.i = ((unsigned int)u) << 16;
    return v.f;
}

// async global->LDS, 16B per lane; LDS dest is wave-uniform base + lane*16
static __device__ __forceinline__ void glds16(const u16* g, u16* l) {
    __builtin_amdgcn_global_load_lds(
        (const __attribute__((address_space(1))) unsigned int*)g,
        (__attribute__((address_space(3))) unsigned int*)l, 16, 0, 0);
}

// ---------------- f32 -> bf16 bulk convert ----------------
__global__ __launch_bounds__(256)
void cvt_kernel(const float* __restrict__ in, u16* __restrict__ out) {
    int i = (blockIdx.x * 256 + threadIdx.x) * 8;
    float4 a = *(const float4*)&in[i];
    float4 b = *(const float4*)&in[i + 4];
    short8 o;
    o[0] = (short)f2bf(a.x); o[1] = (short)f2bf(a.y);
    o[2] = (short)f2bf(a.z); o[3] = (short)f2bf(a.w);
    o[4] = (short)f2bf(b.x); o[5] = (short)f2bf(b.y);
    o[6] = (short)f2bf(b.z); o[7] = (short)f2bf(b.w);
    *(short8*)&out[i] = o;
}

// ---------------- bf16 GEMM core: Y[m][n] = sum_k A[m][k] * W[n][k] ----------------
// 128x128 tile, BK=32, global_load_lds staging, double-buffered linear LDS (m97 pattern).
template<int OUT_F32>
static __device__ __forceinline__
void gemm_core(const u16* __restrict__ A, const u16* __restrict__ W,
               void* __restrict__ Y, int ldY, int mBase, int nBase,
               u16* lA, u16* lB)
{
    const int t    = threadIdx.x;
    const int lane = t & 63, wid = t >> 6;
    const int wr = wid >> 1, wc = wid & 1;
    const int lr = lane & 15, lg = lane >> 4;

    f32x4 acc[4][4] = {};

    const int srow = t >> 2;         // staging row (+64 for j=1)
    const int scol = (t & 3) * 8;    // staging col (u16)
    const u16* Ag = A + (size_t)(mBase + srow) * D_ + scol;
    const u16* Wg = W + (size_t)(nBase + srow) * D_ + scol;
    const int ldsoff = t * 8;        // element offset; +j*2048, +buf*4096

    auto stage = [&](int buf, int kt) {
#pragma unroll
        for (int j = 0; j < 2; ++j) {
            glds16(Ag + (size_t)j * 64 * D_ + kt * 32, lA + buf * 4096 + j * 2048 + ldsoff);
            glds16(Wg + (size_t)j * 64 * D_ + kt * 32, lB + buf * 4096 + j * 2048 + ldsoff);
        }
    };

    stage(0, 0);
    asm volatile("s_waitcnt vmcnt(0)" ::: "memory");
    __syncthreads();

    int cur = 0;
    for (int kt = 0; kt < 32; ++kt) {
        if (kt < 31) stage(cur ^ 1, kt + 1);   // async prefetch into other buffer
        short8 af[4], bfv[4];
#pragma unroll
        for (int m = 0; m < 4; ++m)
            af[m] = *(const short8*)&lA[cur * 4096 + (wr * 64 + m * 16 + lr) * 32 + lg * 8];
#pragma unroll
        for (int n = 0; n < 4; ++n)
            bfv[n] = *(const short8*)&lB[cur * 4096 + (wc * 64 + n * 16 + lr) * 32 + lg * 8];
#pragma unroll
        for (int m = 0; m < 4; ++m)
#pragma unroll
            for (int n = 0; n < 4; ++n)
                acc[m][n] = __builtin_amdgcn_mfma_f32_16x16x32_bf16(af[m], bfv[n], acc[m][n], 0, 0, 0);
        if (kt < 31) {
            asm volatile("s_waitcnt vmcnt(0)" ::: "memory");
            __syncthreads();
        }
        cur ^= 1;
    }

    // epilogue: C layout col=lane&15, row=(lane>>4)*4+reg
#pragma unroll
    for (int m = 0; m < 4; ++m)
#pragma unroll
        for (int n = 0; n < 4; ++n)
#pragma unroll
            for (int r = 0; r < 4; ++r) {
                int row = mBase + wr * 64 + m * 16 + lg * 4 + r;
                int col = nBase + wc * 64 + n * 16 + lr;
                if (OUT_F32)
                    ((float*)Y)[(size_t)row * ldY + col] = acc[m][n][r];
                else
                    ((u16*)Y)[(size_t)row * ldY + col] = f2bf(acc[m][n][r]);
            }
}

// fused QKV: z=0 -> Q = x Wq^T, z=1 -> K = x Wk^T, z=2 -> V^T = Wv x^T (same kernel, swapped)
__global__ __launch_bounds__(256)
void gemm_qkv(const u16* __restrict__ xb, const u16* __restrict__ wq, const u16* __restrict__ wk,
              const u16* __restrict__ wv, u16* __restrict__ Qo, u16* __restrict__ Ko,
              u16* __restrict__ Vto)
{
    __shared__ u16 lA[2 * 128 * 32];
    __shared__ u16 lB[2 * 128 * 32];
    const int z = blockIdx.z;
    if (z == 0)
        gemm_core<0>(xb, wq, Qo, D_, blockIdx.x * 128, blockIdx.y * 128, lA, lB);
    else if (z == 1)
        gemm_core<0>(xb, wk, Ko, D_, blockIdx.x * 128, blockIdx.y * 128, lA, lB);
    else
        gemm_core<0>(wv, xb, Vto, LDV_, blockIdx.y * 128, blockIdx.x * 128, lA, lB);
}

__global__ __launch_bounds__(256)
void gemm_out(const u16* __restrict__ Ab, const u16* __restrict__ wo, float* __restrict__ out)
{
    __shared__ u16 lA[2 * 128 * 32];
    __shared__ u16 lB[2 * 128 * 32];
    gemm_core<1>(Ab, wo, out, D_, blockIdx.x * 128, blockIdx.y * 128, lA, lB);
}

// ---------------- causal flash attention ----------------
// Block handles TWO q-tiles (heavy 31-x, then light x): uniform 33 KV-iters per block.
// K staged [key][hd] (pad 72), V staged from pre-transposed V^T [hd][key] (pad 72):
// all staging is vectorized short8, double-buffered, 1 barrier/iter, prefetch hidden under compute.
__global__ __launch_bounds__(256)
void attn_fwd(const u16* __restrict__ Q, const u16* __restrict__ K,
              const u16* __restrict__ Vt, u16* __restrict__ O)
{
    __shared__ u16 lK[2][64][72];
    __shared__ u16 lV[2][64][72];
    __shared__ u16 lP[4][16][72];

    const int t    = threadIdx.x;
    const int lane = t & 63, wid = t >> 6;
    const int lr = lane & 15, lg = lane >> 4;
    const int bh = blockIdx.y;
    const int b = bh >> 4, h = bh & 15;

    const u16* Qb = Q + (size_t)b * SEQ_ * D_ + h * HD_;
    const u16* Kb = K + (size_t)b * SEQ_ * D_ + h * HD_;
    const u16* Vg = Vt + (size_t)(h * HD_) * LDV_ + b * SEQ_;
    u16*       Ob = O + (size_t)b * SEQ_ * D_ + h * HD_;

    const int sr = t >> 3;          // staging row 0..31 (+32)
    const int sc = (t & 7) * 8;     // staging col

#pragma unroll 1
    for (int half = 0; half < 2; ++half) {
        const int qt = (half == 0) ? (31 - (int)blockIdx.x) : (int)blockIdx.x;
        const int qbase = qt * 64;

        // Q fragments, pre-scaled by 1/sqrt(64)=0.125 (exact in bf16)
        short8 qf[2];
        {
            const int qrow = qbase + wid * 16 + lr;
#pragma unroll
            for (int ks = 0; ks < 2; ++ks) {
                short8 v = *(const short8*)&Qb[(size_t)qrow * D_ + ks * 32 + lg * 8];
#pragma unroll
                for (int i = 0; i < 8; ++i)
                    v[i] = (short)f2bf(bf2f((u16)v[i]) * 0.125f);
                qf[ks] = v;
            }
        }

        f32x4 accO[4] = {};
        float m_r[4], l_r[4];
#pragma unroll
        for (int r = 0; r < 4; ++r) { m_r[r] = -1e30f; l_r[r] = 0.f; }

        // prologue: stage kt=0 into buf 0
        {
            short8 k0 = *(const short8*)&Kb[(size_t)sr * D_ + sc];
            short8 k1 = *(const short8*)&Kb[(size_t)(sr + 32) * D_ + sc];
            short8 v0 = *(const short8*)&Vg[(size_t)sr * LDV_ + sc];
            short8 v1 = *(const short8*)&Vg[(size_t)(sr + 32) * LDV_ + sc];
            *(short8*)&lK[0][sr][sc] = k0;  *(short8*)&lK[0][sr + 32][sc] = k1;
            *(short8*)&lV[0][sr][sc] = v0;  *(short8*)&lV[0][sr + 32][sc] = v1;
        }
        __syncthreads();

        int cur = 0;
        for (int kt = 0; kt <= qt; ++kt) {
            const int kb = kt * 64;
            // issue next-tile global loads early (latency hides under compute)
            short8 k0, k1, v0, v1;
            if (kt < qt) {
                const int kn = kb + 64;
                k0 = *(const short8*)&Kb[(size_t)(kn + sr) * D_ + sc];
                k1 = *(const short8*)&Kb[(size_t)(kn + sr + 32) * D_ + sc];
                v0 = *(const short8*)&Vg[(size_t)sr * LDV_ + kn + sc];
                v1 = *(const short8*)&Vg[(size_t)(sr + 32) * LDV_ + kn + sc];
            }

            // QK^T
            f32x4 s[4] = {};
#pragma unroll
            for (int n = 0; n < 4; ++n)
#pragma unroll
                for (int ks = 0; ks < 2; ++ks) {
                    short8 kf = *(const short8*)&lK[cur][n * 16 + lr][ks * 32 + lg * 8];
                    s[n] = __builtin_amdgcn_mfma_f32_16x16x32_bf16(qf[ks], kf, s[n], 0, 0, 0);
                }
            // causal mask: only the diagonal tile
            if (kt == qt) {
#pragma unroll
                for (int n = 0; n < 4; ++n)
#pragma unroll
                    for (int r = 0; r < 4; ++r)
                        if (kb + n * 16 + lr > qbase + wid * 16 + lg * 4 + r) s[n][r] = -1e30f;
            }
            // online softmax (row r lives on the 16 lanes sharing lg)
            float tmax[4], alpha[4], rs[4];
#pragma unroll
            for (int r = 0; r < 4; ++r) {
                tmax[r] = fmaxf(fmaxf(s[0][r], s[1][r]), fmaxf(s[2][r], s[3][r]));
#pragma unroll
                for (int d = 1; d < 16; d <<= 1)
                    tmax[r] = fmaxf(tmax[r], __shfl_xor(tmax[r], d));
                float mn = fmaxf(m_r[r], tmax[r]);
                alpha[r] = __expf(m_r[r] - mn);
                m_r[r] = mn; rs[r] = 0.f;
            }
#pragma unroll
            for (int n = 0; n < 4; ++n)
#pragma unroll
                for (int r = 0; r < 4; ++r) {
                    float p = __expf(s[n][r] - m_r[r]);
                    s[n][r] = p;
                    rs[r] += p;
                }
#pragma unroll
            for (int r = 0; r < 4; ++r) {
#pragma unroll
                for (int d = 1; d < 16; d <<= 1) rs[r] += __shfl_xor(rs[r], d);
                l_r[r] = l_r[r] * alpha[r] + rs[r];
            }
            // P -> per-wave LDS (no barrier needed: same-wave RAW), rescale O
#pragma unroll
            for (int n = 0; n < 4; ++n)
#pragma unroll
                for (int r = 0; r < 4; ++r) {
                    lP[wid][lg * 4 + r][n * 16 + lr] = f2bf(s[n][r]);
                    accO[n][r] *= alpha[r];
                }
            // PV
#pragma unroll
            for (int ks = 0; ks < 2; ++ks) {
                short8 pa = *(const short8*)&lP[wid][lr][ks * 32 + lg * 8];
#pragma unroll
                for (int n = 0; n < 4; ++n) {
                    short8 vf = *(const short8*)&lV[cur][n * 16 + lr][ks * 32 + lg * 8];
                    accO[n] = __builtin_amdgcn_mfma_f32_16x16x32_bf16(pa, vf, accO[n], 0, 0, 0);
                }
            }
            // write prefetched tile into the other buffer (its readers finished last iter)
            if (kt < qt) {
                *(short8*)&lK[cur ^ 1][sr][sc] = k0;  *(short8*)&lK[cur ^ 1][sr + 32][sc] = k1;
                *(short8*)&lV[cur ^ 1][sr][sc] = v0;  *(short8*)&lV[cur ^ 1][sr + 32][sc] = v1;
            }
            __syncthreads();
            cur ^= 1;
        }

        // epilogue: O = acc / l
#pragma unroll
        for (int n = 0; n < 4; ++n)
#pragma unroll
            for (int r = 0; r < 4; ++r) {
                int qr = qbase + wid * 16 + lg * 4 + r;
                Ob[(size_t)qr * D_ + n * 16 + lr] = f2bf(accO[n][r] / l_r[r]);
            }
        // loop's final __syncthreads already separates halves
    }
}

extern "C" void kernel_launch(void* const* d_in, const int* in_sizes, int n_in,
                              void* d_out, int out_size, void* d_ws, size_t ws_size,
                              hipStream_t stream)
{
    const float* x  = (const float*)d_in[0];
    const float* Wq = (const float*)d_in[1];
    const float* Wk = (const float*)d_in[2];
    const float* Wv = (const float*)d_in[3];
    const float* Wo = (const float*)d_in[4];
    float* out = (float*)d_out;

    const size_t NX = (size_t)NB_ * SEQ_ * D_;  // 4194304
    const size_t NW = (size_t)D_ * D_;          // 1048576

    u16* xb  = (u16*)d_ws;
    u16* wqb = xb  + NX;
    u16* wkb = wqb + NW;
    u16* wvb = wkb + NW;
    u16* wob = wvb + NW;
    u16* Qb  = wob + NW;
    u16* Kb  = Qb  + NX;
    u16* Vtb = Kb  + NX;   // V^T: [1024][4096]
    u16* Ab  = Vtb + NX;

    cvt_kernel<<<dim3(NX / 2048), dim3(256), 0, stream>>>(x,  xb);
    cvt_kernel<<<dim3(NW / 2048), dim3(256), 0, stream>>>(Wq, wqb);
    cvt_kernel<<<dim3(NW / 2048), dim3(256), 0, stream>>>(Wk, wkb);
    cvt_kernel<<<dim3(NW / 2048), dim3(256), 0, stream>>>(Wv, wvb);
    cvt_kernel<<<dim3(NW / 2048), dim3(256), 0, stream>>>(Wo, wob);

    // fused QKV projection (z=2 computes V^T directly)
    gemm_qkv<<<dim3(32, 8, 3), dim3(256), 0, stream>>>(xb, wqb, wkb, wvb, Qb, Kb, Vtb);

    // causal flash attention, load-balanced q-tile pairs
    attn_fwd<<<dim3(16, 32), dim3(256), 0, stream>>>(Qb, Kb, Vtb, Ab);

    // output projection -> f32
    gemm_out<<<dim3(32, 8, 1), dim3(256), 0, stream>>>(Ab, wob, out);
}